// Round 2
// baseline (530.337 us; speedup 1.0000x reference)
//
#include <hip/hip_runtime.h>
#include <hip/hip_bf16.h>
#include <stdint.h>

// WaveletLinearLayer: out = HaarDWT2(x) @ W.T + b
// == fused split-K GEMM: out[m,n] = b[n] + 0.5 * sum_k u[m,k]*W[n,k],
// u = unscaled Haar combos of 2x2 spatial quads of x.
// M=256, N=64, K=262144. Memory-bound: 335 MB compulsory.
//
// R2: LDS-free / barrier-free. Within-step K order re-mapped to
// k_local = jl*4 + q so each lane's A-fragment is one contiguous x quad
// (2x float4, Haar+pack in regs, no duplication). B-fragments from 4x float2
// W loads per fragment; the 8x per-block wave duplication of the 16 KB W
// tile is L1-resident. No __syncthreads -> no vmcnt(0) barrier drains.

#define IN_K 262144

typedef short bf16x8 __attribute__((ext_vector_type(8)));
typedef float f32x4  __attribute__((ext_vector_type(4)));

__device__ __forceinline__ uint32_t pack2_bf16(float a, float b) {
    // round-to-nearest-even fp32 -> bf16, packed low(a)|high(b)
    uint32_t ua = __float_as_uint(a);
    uint32_t ub = __float_as_uint(b);
    ua = (ua + 0x7fffu + ((ua >> 16) & 1u)) >> 16;
    ub = (ub + 0x7fffu + ((ub >> 16) & 1u)) >> 16;
    return ua | (ub << 16);
}

// Grid-stride over 4096 K-steps. Step s -> (c,i,jg): channel c in [0,4),
// spatial row-pair i in [0,128), j-group jg in [0,8) (16 jl's x 4 subbands
// = 64 k per step). k_local = jl_local*4 + q.
__global__ __launch_bounds__(512) void wavelet_gemm(
    const float* __restrict__ x, const float* __restrict__ W,
    float* __restrict__ part)
{
    const int tid  = threadIdx.x;
    const int lane = tid & 63;
    const int wave = tid >> 6;       // 8 waves: each does 32 rows x 64 cols
    const int l16  = lane & 15;
    const int l4   = lane >> 4;
    const int wm   = wave * 32;

    f32x4 acc[2][4];
#pragma unroll
    for (int mi = 0; mi < 2; mi++)
#pragma unroll
        for (int ni = 0; ni < 4; ni++)
            acc[mi][ni] = (f32x4){0.f, 0.f, 0.f, 0.f};

    for (int s = blockIdx.x; s < 4096; s += gridDim.x) {
        const int ci = s >> 3;
        const int jg = s & 7;
        const int c  = ci >> 7;
        const int i  = ci & 127;

        // x: row m, flat offset c*65536 + (2i)*256 + 32*jg (+16*kh + 4*l4)
        const int xoff = c * 65536 + 2 * i * 256 + 32 * jg + 4 * l4;
        // W: row n, t-col = c*65536 + q*16384 + i*128 + 16*jg + jl,
        //    jl = 8*kh + 2*l4 (+1)
        const int woff = c * 65536 + i * 128 + 16 * jg + 2 * l4;

        // ---- B fragments: bfrag[kh][ni], element j: q=j&3, jl+=(j>>2) ----
        bf16x8 bfrag[2][4];
#pragma unroll
        for (int kh = 0; kh < 2; kh++) {
#pragma unroll
            for (int ni = 0; ni < 4; ni++) {
                const float* wp = W + (size_t)(ni * 16 + l16) * IN_K
                                    + woff + 8 * kh;
                const float2 v0 = *(const float2*)(wp);
                const float2 v1 = *(const float2*)(wp + 16384);
                const float2 v2 = *(const float2*)(wp + 32768);
                const float2 v3 = *(const float2*)(wp + 49152);
                union { bf16x8 v; uint32_t u[4]; } bu;
                bu.u[0] = pack2_bf16(v0.x, v1.x);   // e0=q0@jl, e1=q1@jl
                bu.u[1] = pack2_bf16(v2.x, v3.x);   // e2=q2@jl, e3=q3@jl
                bu.u[2] = pack2_bf16(v0.y, v1.y);   // e4..e7 @ jl+1
                bu.u[3] = pack2_bf16(v2.y, v3.y);
                bfrag[kh][ni] = bu.v;
            }
        }

        // ---- A fragments: afrag[mi][kh] from one x quad-pair per lane ----
        bf16x8 afrag[2][2];
#pragma unroll
        for (int mi = 0; mi < 2; mi++) {
            const float* xp = x + (size_t)(wm + mi * 16 + l16) * IN_K + xoff;
#pragma unroll
            for (int kh = 0; kh < 2; kh++) {
                const float4 f0 = *(const float4*)(xp + 16 * kh);        // row 2i
                const float4 f1 = *(const float4*)(xp + 16 * kh + 256);  // row 2i+1
                // quad1: a=f0.x b=f0.y c=f1.x d=f1.y ; quad2: .z/.w
                const float s1 = f0.x + f0.y, d1 = f0.x - f0.y;
                const float s2 = f1.x + f1.y, d2 = f1.x - f1.y;
                const float t1 = f0.z + f0.w, e1 = f0.z - f0.w;
                const float t2 = f1.z + f1.w, e2 = f1.z - f1.w;
                union { bf16x8 v; uint32_t u[4]; } au;
                au.u[0] = pack2_bf16(s1 + s2, s1 - s2);  // LL, LH  (quad1)
                au.u[1] = pack2_bf16(d1 + d2, d1 - d2);  // HL, HH
                au.u[2] = pack2_bf16(t1 + t2, t1 - t2);  // LL, LH  (quad2)
                au.u[3] = pack2_bf16(e1 + e2, e1 - e2);  // HL, HH
                afrag[mi][kh] = au.v;
            }
        }

        // ---- MFMA: 16 per wave per step ----
#pragma unroll
        for (int kh = 0; kh < 2; kh++)
#pragma unroll
            for (int ni = 0; ni < 4; ni++) {
                acc[0][ni] = __builtin_amdgcn_mfma_f32_16x16x32_bf16(
                    afrag[0][kh], bfrag[kh][ni], acc[0][ni], 0, 0, 0);
                acc[1][ni] = __builtin_amdgcn_mfma_f32_16x16x32_bf16(
                    afrag[1][kh], bfrag[kh][ni], acc[1][ni], 0, 0, 0);
            }
    }

    // ---- epilogue: write 256x64 partial for this block ----
    // C/D layout: col = lane&15, row = (lane>>4)*4 + r
    float* p = part + (size_t)blockIdx.x * (256 * 64);
#pragma unroll
    for (int mi = 0; mi < 2; mi++)
#pragma unroll
        for (int ni = 0; ni < 4; ni++)
#pragma unroll
            for (int r = 0; r < 4; r++) {
                const int m = wm + mi * 16 + l4 * 4 + r;
                const int n = ni * 16 + l16;
                p[m * 64 + n] = acc[mi][ni][r];
            }
}

// out[e] = bias[e&63] + 0.5 * sum_blk part[blk][e]
__global__ __launch_bounds__(256) void wavelet_reduce(
    const float* __restrict__ part, const float* __restrict__ bias,
    float* __restrict__ out, int nblk)
{
    __shared__ float red[4][64];
    const int e_l = threadIdx.x & 63;
    const int g   = threadIdx.x >> 6;
    const int e0  = blockIdx.x * 64;
    float acc = 0.f;
#pragma unroll 8
    for (int blk = g; blk < nblk; blk += 4)
        acc += part[(size_t)blk * 16384 + e0 + e_l];
    red[g][e_l] = acc;
    __syncthreads();
    if (g == 0) {
        const float v = red[0][e_l] + red[1][e_l] + red[2][e_l] + red[3][e_l];
        out[e0 + e_l] = 0.5f * v + bias[e_l];
    }
}

extern "C" void kernel_launch(void* const* d_in, const int* in_sizes, int n_in,
                              void* d_out, int out_size, void* d_ws, size_t ws_size,
                              hipStream_t stream)
{
    const float* x = (const float*)d_in[0];   // (256, 262144) fp32
    const float* W = (const float*)d_in[1];   // (64, 262144) fp32
    const float* b = (const float*)d_in[2];   // (64,) fp32
    float* out  = (float*)d_out;              // (256, 64) fp32
    float* part = (float*)d_ws;

    int nb = (int)(ws_size / (size_t)(16384 * 4));
    if (nb > 512) nb = 512;
    if (nb < 1)  nb = 1;

    wavelet_gemm<<<nb, 512, 0, stream>>>(x, W, part);
    wavelet_reduce<<<256, 256, 0, stream>>>(part, b, out, nb);
}

// Round 3
// 441.929 us; speedup vs baseline: 1.2001x; 1.2001x over previous
//
#include <hip/hip_runtime.h>
#include <hip/hip_bf16.h>
#include <stdint.h>

// WaveletLinearLayer: out = HaarDWT2(x) @ W.T + b
// == split GEMM: out[m,n] = b[n] + 0.5 * sum_k u[m,k]*W[n,k],
// u = unscaled Haar combos of 2x2 spatial quads of x. M=256,N=64,K=262144.
//
// R3: long-run streaming. Block = (mh,c,i,jh): M=64, K=256, N=64, one-shot
// LDS stage (A 33KB + B 33KB = 67.6KB -> 2 blocks/CU), ONE barrier, MFMA,
// 16KB fp32 partial. Every global load instr covers >=512B contiguous runs
// (vs 64B scattered runs in R1/R2 which capped at ~1.2 TB/s).
// x read once (268MB); W read 4x but L3-resident (64MB); partials 64MB w+r.

#define IN_K  262144
#define PITCH 264   // LDS row pitch in shorts; 264=4 mod 32 banks -> 2-way max

typedef short bf16x8 __attribute__((ext_vector_type(8)));
typedef float f32x4  __attribute__((ext_vector_type(4)));

__device__ __forceinline__ uint32_t pack2_bf16(float a, float b) {
    uint32_t ua = __float_as_uint(a);
    uint32_t ub = __float_as_uint(b);
    ua = (ua + 0x7fffu + ((ua >> 16) & 1u)) >> 16;
    ub = (ub + 0x7fffu + ((ub >> 16) & 1u)) >> 16;
    return ua | (ub << 16);
}

// k_local = (j - 64*jh)*4 + q mapping, j = global spatial col index pair.
__global__ __launch_bounds__(512, 4) void wavelet_gemm(
    const float* __restrict__ x, const float* __restrict__ W,
    float* __restrict__ part)
{
    __shared__ short Ash[64 * PITCH];   // A: u[m_l][k], 33792 B
    __shared__ short Bsh[64 * PITCH];   // B: W[n][k],   33792 B

    const int tid  = threadIdx.x;
    const int lane = tid & 63;
    const int l16  = lane & 15;
    const int l4   = lane >> 4;
    const int wave = tid >> 6;          // 8 waves

    const int b  = blockIdx.x;          // 4096 blocks
    const int mh = b & 3;               // fastest: 4 mh siblings share W tile
    const int s  = b >> 2;              // (c,i,jh)
    const int jh = s & 1;
    const int i  = (s >> 1) & 127;
    const int c  = s >> 8;

    // ---- stage x -> Ash (Haar in-lane, 512B runs) ----
    // per r: 64 lanes cover 2 m-rows x 32 float4 (two 512B runs per instr)
    const float* xbase = x + (size_t)mh * 64 * IN_K
                           + c * 65536 + 2 * i * 256 + 128 * jh;
#pragma unroll
    for (int r = 0; r < 4; r++) {
        const int p   = tid + 512 * r;
        const int m_l = p >> 5;          // 0..63
        const int jj4 = p & 31;          // float4 index within 128-col chunk
        const float* xp = xbase + (size_t)m_l * IN_K + 4 * jj4;
        const float4 f0 = *(const float4*)(xp);         // row 2i
        const float4 f1 = *(const float4*)(xp + 256);   // row 2i+1
        const float s1 = f0.x + f0.y, d1 = f0.x - f0.y;
        const float s2 = f1.x + f1.y, d2 = f1.x - f1.y;
        const float t1 = f0.z + f0.w, e1 = f0.z - f0.w;
        const float t2 = f1.z + f1.w, e2 = f1.z - f1.w;
        union { bf16x8 v; uint32_t u[4]; } au;
        au.u[0] = pack2_bf16(s1 + s2, s1 - s2);  // k=8jj4+0,1 (LL,LH quad1)
        au.u[1] = pack2_bf16(d1 + d2, d1 - d2);  // k=8jj4+2,3 (HL,HH)
        au.u[2] = pack2_bf16(t1 + t2, t1 - t2);  // k=8jj4+4,5 (quad2)
        au.u[3] = pack2_bf16(e1 + e2, e1 - e2);  // k=8jj4+6,7
        *(bf16x8*)&Ash[m_l * PITCH + 8 * jj4] = au.v;
    }

    // ---- stage W -> Bsh (4 q-streams, 256B runs, k-contiguous pack) ----
    // slot=(n,jlq): 4 float4 loads (q=0..3) -> 16 consecutive k -> 2x b128
    const float* wbase = W + c * 65536 + i * 128 + 64 * jh;
#pragma unroll
    for (int r = 0; r < 2; r++) {
        const int slot = tid + 512 * r;
        const int n    = slot >> 4;
        const int jlq  = slot & 15;
        const float* wp = wbase + (size_t)n * IN_K + 4 * jlq;
        const float4 v0 = *(const float4*)(wp);
        const float4 v1 = *(const float4*)(wp + 16384);
        const float4 v2 = *(const float4*)(wp + 32768);
        const float4 v3 = *(const float4*)(wp + 49152);
        union { bf16x8 v; uint32_t u[4]; } b0, b1;
        b0.u[0] = pack2_bf16(v0.x, v1.x);  // k=16jlq+0,1  (q0,q1 @ e0)
        b0.u[1] = pack2_bf16(v2.x, v3.x);  // k=16jlq+2,3  (q2,q3 @ e0)
        b0.u[2] = pack2_bf16(v0.y, v1.y);  // e1
        b0.u[3] = pack2_bf16(v2.y, v3.y);
        b1.u[0] = pack2_bf16(v0.z, v1.z);  // e2
        b1.u[1] = pack2_bf16(v2.z, v3.z);
        b1.u[2] = pack2_bf16(v0.w, v1.w);  // e3
        b1.u[3] = pack2_bf16(v2.w, v3.w);
        *(bf16x8*)&Bsh[n * PITCH + 16 * jlq]     = b0.v;
        *(bf16x8*)&Bsh[n * PITCH + 16 * jlq + 8] = b1.v;
    }

    __syncthreads();   // the ONE barrier

    // ---- MFMA: wave -> 16m x 32n tile, K=256 ----
    const int tm = wave & 3;     // m-tile
    const int nh = wave >> 2;    // n-half
    f32x4 acc0 = (f32x4){0.f, 0.f, 0.f, 0.f};
    f32x4 acc1 = (f32x4){0.f, 0.f, 0.f, 0.f};
#pragma unroll
    for (int kh = 0; kh < 8; kh++) {
        const int ko = kh * 32 + l4 * 8;
        bf16x8 a  = *(const bf16x8*)&Ash[(tm * 16 + l16) * PITCH + ko];
        bf16x8 b0 = *(const bf16x8*)&Bsh[(nh * 32 + l16) * PITCH + ko];
        bf16x8 b1 = *(const bf16x8*)&Bsh[(nh * 32 + 16 + l16) * PITCH + ko];
        acc0 = __builtin_amdgcn_mfma_f32_16x16x32_bf16(a, b0, acc0, 0, 0, 0);
        acc1 = __builtin_amdgcn_mfma_f32_16x16x32_bf16(a, b1, acc1, 0, 0, 0);
    }

    // ---- write 64x64 fp32 partial ----
    // C/D: col = lane&15, row = (lane>>4)*4 + r
    float* pp = part + (size_t)b * 4096;
#pragma unroll
    for (int r = 0; r < 4; r++) {
        const int m = tm * 16 + l4 * 4 + r;
        pp[m * 64 + nh * 32 + l16]      = acc0[r];
        pp[m * 64 + nh * 32 + 16 + l16] = acc1[r];
    }
}

// out[m][n] = bias[n] + 0.5 * sum_{s=0}^{1023} part[s*4 + (m>>6)][m&63][n]
__global__ __launch_bounds__(512) void wavelet_reduce(
    const float* __restrict__ part, const float* __restrict__ bias,
    float* __restrict__ out)
{
    __shared__ float red[8][64];
    const int m  = blockIdx.x;          // 256
    const int mh = m >> 6;
    const int ml = m & 63;
    const int n  = threadIdx.x & 63;
    const int g  = threadIdx.x >> 6;    // 8 groups
    const float* base = part + (size_t)ml * 64 + n + (size_t)mh * 4096;
    float acc = 0.f;
#pragma unroll 4
    for (int s = g; s < 1024; s += 8)
        acc += base[(size_t)s * 4 * 4096];
    red[g][n] = acc;
    __syncthreads();
    if (g == 0) {
        float v = red[0][n] + red[1][n] + red[2][n] + red[3][n]
                + red[4][n] + red[5][n] + red[6][n] + red[7][n];
        out[m * 64 + n] = 0.5f * v + bias[n];
    }
}

extern "C" void kernel_launch(void* const* d_in, const int* in_sizes, int n_in,
                              void* d_out, int out_size, void* d_ws, size_t ws_size,
                              hipStream_t stream)
{
    const float* x = (const float*)d_in[0];   // (256, 262144) fp32
    const float* W = (const float*)d_in[1];   // (64, 262144) fp32
    const float* b = (const float*)d_in[2];   // (64,) fp32
    float* out  = (float*)d_out;              // (256, 64) fp32
    float* part = (float*)d_ws;               // 4096 * 16 KB = 64 MB

    wavelet_gemm<<<4096, 512, 0, stream>>>(x, W, part);
    wavelet_reduce<<<256, 512, 0, stream>>>(part, b, out);
}

// Round 4
// 428.820 us; speedup vs baseline: 1.2367x; 1.0306x over previous
//
#include <hip/hip_runtime.h>
#include <hip/hip_bf16.h>
#include <stdint.h>

// WaveletLinearLayer: out = HaarDWT2(x) @ W.T + b
// == split GEMM: out[m,n] = b[n] + 0.5 * sum_k u[m,k]*W[n,k],
// u = unscaled Haar combos of 2x2 spatial quads of x. M=256,N=64,K=262144.
//
// R4: persistent blocks + sequential streams + reg-pipelined staging.
// 512 blocks (2/CU), block=(mh, c, i-group of 4): 8 K-chunks of 256, each
// x row-stream reads 8KB sequentially across the block's chunks; W streams
// 2KB sequential. Accumulate across chunks -> partials 64MB -> 8MB.
// Pipeline: preload regs; {pack->LDS; barrier; load t+1; MFMA; barrier}.

#define IN_K  262144
#define PITCH 264   // LDS row pitch in shorts; 264 = 4 mod 32 banks -> 2-way max

typedef short bf16x8 __attribute__((ext_vector_type(8)));
typedef float f32x4  __attribute__((ext_vector_type(4)));

__device__ __forceinline__ uint32_t pack2_bf16(float a, float b) {
    uint32_t ua = __float_as_uint(a);
    uint32_t ub = __float_as_uint(b);
    ua = (ua + 0x7fffu + ((ua >> 16) & 1u)) >> 16;
    ub = (ub + 0x7fffu + ((ub >> 16) & 1u)) >> 16;
    return ua | (ub << 16);
}

__global__ __launch_bounds__(512, 4) void wavelet_gemm(
    const float* __restrict__ x, const float* __restrict__ W,
    float* __restrict__ part)
{
    __shared__ short Ash[64 * PITCH];   // u[m_l][k] bf16, 33792 B
    __shared__ short Bsh[64 * PITCH];   // W[n][k]  bf16, 33792 B

    const int tid  = threadIdx.x;
    const int lane = tid & 63;
    const int l16  = lane & 15;
    const int l4   = lane >> 4;
    const int wave = tid >> 6;          // 8 waves

    const int b    = blockIdx.x;        // 512 blocks
    const int mh   = b & 3;             // adjacent mh-siblings share W stream
    const int widx = b >> 2;            // 0..127
    const int c    = widx >> 5;         // channel 0..3
    const int ig   = widx & 31;         // i-group: i = 4*ig .. 4*ig+3

    const float* xm  = x + (size_t)(mh * 64) * IN_K + c * 65536;
    const float* wcb = W + c * 65536;

    // per-thread invariant staging coords
    const int a_m  = tid >> 5;          // A: m_l = a_m + 16*r
    const int a_j4 = tid & 31;          // float4 index in 128-col chunk
    const int b_n  = tid >> 4;          // B: n = b_n + 32*r
    const int b_j  = tid & 15;          // jlq

    float4 af[4][2];                    // A load buffer (32 VGPRs)
    float4 bf[2][4];                    // B load buffer (32 VGPRs)

    auto load_chunk = [&](int t) {
        const int i  = ig * 4 + (t >> 1);
        const int jh = t & 1;
        const float* xc = xm + 2 * i * 256 + 128 * jh;
#pragma unroll
        for (int r = 0; r < 4; r++) {
            const float* xp = xc + (size_t)(a_m + 16 * r) * IN_K + 4 * a_j4;
            af[r][0] = *(const float4*)(xp);         // row 2i
            af[r][1] = *(const float4*)(xp + 256);   // row 2i+1
        }
        const float* wc = wcb + i * 128 + 64 * jh;
#pragma unroll
        for (int r = 0; r < 2; r++) {
            const float* wp = wc + (size_t)(b_n + 32 * r) * IN_K + 4 * b_j;
            bf[r][0] = *(const float4*)(wp);
            bf[r][1] = *(const float4*)(wp + 16384);
            bf[r][2] = *(const float4*)(wp + 32768);
            bf[r][3] = *(const float4*)(wp + 49152);
        }
    };

    auto stage = [&]() {
#pragma unroll
        for (int r = 0; r < 4; r++) {
            const float4 f0 = af[r][0], f1 = af[r][1];
            const float s1 = f0.x + f0.y, d1 = f0.x - f0.y;
            const float s2 = f1.x + f1.y, d2 = f1.x - f1.y;
            const float t1 = f0.z + f0.w, e1 = f0.z - f0.w;
            const float t2 = f1.z + f1.w, e2 = f1.z - f1.w;
            union { bf16x8 v; uint32_t u[4]; } au;
            au.u[0] = pack2_bf16(s1 + s2, s1 - s2);  // k=8j4+0,1 (LL,LH q1)
            au.u[1] = pack2_bf16(d1 + d2, d1 - d2);  // k=8j4+2,3 (HL,HH)
            au.u[2] = pack2_bf16(t1 + t2, t1 - t2);  // quad2
            au.u[3] = pack2_bf16(e1 + e2, e1 - e2);
            *(bf16x8*)&Ash[(a_m + 16 * r) * PITCH + 8 * a_j4] = au.v;
        }
#pragma unroll
        for (int r = 0; r < 2; r++) {
            const float4 v0 = bf[r][0], v1 = bf[r][1];
            const float4 v2 = bf[r][2], v3 = bf[r][3];
            union { bf16x8 v; uint32_t u[4]; } b0, b1;
            b0.u[0] = pack2_bf16(v0.x, v1.x);  // k=16jlq+0,1
            b0.u[1] = pack2_bf16(v2.x, v3.x);  // k=16jlq+2,3
            b0.u[2] = pack2_bf16(v0.y, v1.y);
            b0.u[3] = pack2_bf16(v2.y, v3.y);
            b1.u[0] = pack2_bf16(v0.z, v1.z);
            b1.u[1] = pack2_bf16(v2.z, v3.z);
            b1.u[2] = pack2_bf16(v0.w, v1.w);
            b1.u[3] = pack2_bf16(v2.w, v3.w);
            short* br = &Bsh[(b_n + 32 * r) * PITCH + 16 * b_j];
            *(bf16x8*)(br)     = b0.v;
            *(bf16x8*)(br + 8) = b1.v;
        }
    };

    const int tm = wave & 3;     // m-tile within 64
    const int nh = wave >> 2;    // n-half
    f32x4 acc0 = (f32x4){0.f, 0.f, 0.f, 0.f};
    f32x4 acc1 = (f32x4){0.f, 0.f, 0.f, 0.f};

    load_chunk(0);
#pragma unroll 1
    for (int t = 0; t < 8; t++) {
        stage();
        __syncthreads();
        if (t < 7) load_chunk(t + 1);   // in flight during MFMA + barrier
#pragma unroll
        for (int kh = 0; kh < 8; kh++) {
            const int ko = kh * 32 + l4 * 8;
            bf16x8 a  = *(const bf16x8*)&Ash[(tm * 16 + l16) * PITCH + ko];
            bf16x8 bb0 = *(const bf16x8*)&Bsh[(nh * 32 + l16) * PITCH + ko];
            bf16x8 bb1 = *(const bf16x8*)&Bsh[(nh * 32 + 16 + l16) * PITCH + ko];
            acc0 = __builtin_amdgcn_mfma_f32_16x16x32_bf16(a, bb0, acc0, 0, 0, 0);
            acc1 = __builtin_amdgcn_mfma_f32_16x16x32_bf16(a, bb1, acc1, 0, 0, 0);
        }
        __syncthreads();
    }

    // ---- write 64x64 fp32 partial (C/D: col=lane&15, row=(lane>>4)*4+r) ----
    float* pp = part + (size_t)b * 4096;
#pragma unroll
    for (int r = 0; r < 4; r++) {
        const int m = tm * 16 + l4 * 4 + r;
        pp[m * 64 + nh * 32 + l16]      = acc0[r];
        pp[m * 64 + nh * 32 + 16 + l16] = acc1[r];
    }
}

// out[m][n] = bias[n] + 0.5 * sum_{w=0}^{127} part[(w*4 + m>>6)][m&63][n]
__global__ __launch_bounds__(256) void wavelet_reduce(
    const float* __restrict__ part, const float* __restrict__ bias,
    float* __restrict__ out)
{
    __shared__ float red[4][64];
    const int m  = blockIdx.x;          // 256
    const int mh = m >> 6;
    const int ml = m & 63;
    const int n  = threadIdx.x & 63;
    const int g  = threadIdx.x >> 6;    // 4 groups
    const float* base = part + (size_t)mh * 4096 + ml * 64 + n;
    float acc = 0.f;
#pragma unroll 4
    for (int w = g; w < 128; w += 4)
        acc += base[(size_t)w * 16384];
    red[g][n] = acc;
    __syncthreads();
    if (g == 0) {
        const float v = red[0][n] + red[1][n] + red[2][n] + red[3][n];
        out[m * 64 + n] = 0.5f * v + bias[n];
    }
}

extern "C" void kernel_launch(void* const* d_in, const int* in_sizes, int n_in,
                              void* d_out, int out_size, void* d_ws, size_t ws_size,
                              hipStream_t stream)
{
    const float* x = (const float*)d_in[0];   // (256, 262144) fp32
    const float* W = (const float*)d_in[1];   // (64, 262144) fp32
    const float* b = (const float*)d_in[2];   // (64,) fp32
    float* out  = (float*)d_out;              // (256, 64) fp32
    float* part = (float*)d_ws;               // 512 * 16 KB = 8 MB

    wavelet_gemm<<<512, 512, 0, stream>>>(x, W, part);
    wavelet_reduce<<<256, 256, 0, stream>>>(part, b, out);
}